// Round 11
// baseline (304.751 us; speedup 1.0000x reference)
//
#include <hip/hip_runtime.h>
#include <hip/hip_bf16.h>

#define B_ 4
#define S_ 1024
#define D_ 256
#define H_ 8
#define LRELU_ALPHA 0.2f
#define MAXDEG 128

typedef __attribute__((ext_vector_type(8))) short short8;
typedef __attribute__((ext_vector_type(4))) float floatx4;

__device__ __forceinline__ float bf2f(unsigned short u) {
    union { unsigned int i; float f; } c; c.i = ((unsigned int)u) << 16; return c.f;
}
__device__ __forceinline__ unsigned short f2bf(float f) {
    union { float f; unsigned int u; } c; c.f = f;
    unsigned int r = (c.u + 0x7FFF + ((c.u >> 16) & 1)) >> 16;
    return (unsigned short)r;
}

// ---------- fused prep: CSR + x-cast + weight transposes + wvec2 + ACC zeroing ----------
__device__ void castT_body(const float* __restrict__ W, unsigned short* __restrict__ out,
                           int K, int N, int k0, int n0, float (*t)[33], int tid) {
    int tx = tid & 31, ty = tid >> 5;
#pragma unroll
    for (int i = 0; i < 4; ++i)
        t[ty + 8 * i][tx] = W[(size_t)(k0 + ty + 8 * i) * N + n0 + tx];
    __syncthreads();
#pragma unroll
    for (int i = 0; i < 4; ++i)
        out[(size_t)(n0 + ty + 8 * i) * K + k0 + tx] = f2bf(t[tx][ty + 8 * i]);
}

__global__ __launch_bounds__(256) void k_prep(
        const float* __restrict__ x, unsigned short* __restrict__ xb,
        const float* __restrict__ W0, unsigned short* __restrict__ W0t,
        const float* __restrict__ W1, unsigned short* __restrict__ W1t,
        const float* __restrict__ W2, unsigned short* __restrict__ W2t,
        const float* __restrict__ F1, unsigned short* __restrict__ F1t,
        const float* __restrict__ F2, unsigned short* __restrict__ F2t,
        const float* __restrict__ as2, const float* __restrict__ ad2,
        float* __restrict__ WS2, float* __restrict__ WD2,
        const float* __restrict__ adj, int* __restrict__ nbr, int* __restrict__ cnt,
        float* __restrict__ ACC, float* __restrict__ ACC2) {
    __shared__ float t[32][33];
    __shared__ int c;
    int b = blockIdx.x, tid = threadIdx.x;
    if (b < 1024) {                       // x -> bf16
        int i = b * 256 + tid;
        float4 v = ((const float4*)x)[i];
        ushort4 u; u.x = f2bf(v.x); u.y = f2bf(v.y); u.z = f2bf(v.z); u.w = f2bf(v.w);
        ((ushort4*)xb)[i] = u;
    } else if (b < 1088) {                // W0^T
        int i = b - 1024; castT_body(W0, W0t, 256, 256, (i & 7) * 32, (i >> 3) * 32, t, tid);
    } else if (b < 1152) {                // W1^T
        int i = b - 1088; castT_body(W1, W1t, 256, 256, (i & 7) * 32, (i >> 3) * 32, t, tid);
    } else if (b < 1664) {                // W2 per-head transpose
        int i = b - 1152;
        int k0 = (i & 7) * 32, d0 = ((i >> 3) & 7) * 32, h = i >> 6;
        int tx = tid & 31, ty = tid >> 5;
#pragma unroll
        for (int q = 0; q < 4; ++q)
            t[ty + 8 * q][tx] = W2[(size_t)(k0 + ty + 8 * q) * 2048 + h * 256 + d0 + tx];
        __syncthreads();
#pragma unroll
        for (int q = 0; q < 4; ++q)
            W2t[(size_t)(d0 + ty + 8 * q) * 2048 + h * 256 + k0 + tx] = f2bf(t[tx][ty + 8 * q]);
    } else if (b < 1792) {                // ff_w1^T
        int i = b - 1664; castT_body(F1, F1t, 256, 512, (i & 7) * 32, (i >> 3) * 32, t, tid);
    } else if (b < 1920) {                // ff_w2^T
        int i = b - 1792; castT_body(F2, F2t, 512, 256, (i & 15) * 32, (i >> 4) * 32, t, tid);
    } else if (b < 1928) {                // wvec2
        int h = b - 1920, k = tid;
        const float* wrow = W2 + (size_t)k * 2048 + h * 256;
        float s = 0.f, d = 0.f;
        for (int dd = 0; dd < 256; ++dd) {
            float w = wrow[dd];
            s += w * as2[h * 256 + dd];
            d += w * ad2[h * 256 + dd];
        }
        WS2[h * 256 + k] = s;
        WD2[h * 256 + k] = d;
    } else if (b < 6024) {                // CSR build (float4 scan)
        int row = b - 1928;
        if (tid == 0) c = 0;
        __syncthreads();
        float4 a4 = ((const float4*)(adj + (size_t)row * S_))[tid];
#pragma unroll
        for (int q = 0; q < 4; ++q) {
            float a = q == 0 ? a4.x : q == 1 ? a4.y : q == 2 ? a4.z : a4.w;
            if (a > 0.f) {
                int s = atomicAdd(&c, 1);
                if (s < MAXDEG) nbr[row * MAXDEG + s] = tid * 4 + q;
            }
        }
        __syncthreads();
        if (tid == 0) cnt[row] = c < MAXDEG ? c : MAXDEG;
    } else if (b < 6280) {                // zero ACC (1M floats)
        float4 z = make_float4(0.f, 0.f, 0.f, 0.f);
        float4* p = (float4*)ACC + (size_t)(b - 6024) * 1024 + tid;
        p[0] = z; p[256] = z; p[512] = z; p[768] = z;
    } else {                              // zero ACC2 (2M floats)
        float4 z = make_float4(0.f, 0.f, 0.f, 0.f);
        float4* p = (float4*)ACC2 + (size_t)(b - 6280) * 1024 + tid;
        p[0] = z; p[256] = z; p[512] = z; p[768] = z;
    }
}

// ------- wide-tile split-K MFMA GEMM with atomic fp32 accumulation into ACC -------
// grid (N/256, M/64, nsplit); Kc = K/nsplit. ACC must be zeroed beforehand.
__global__ __launch_bounds__(256) void k_gemm_wide(const unsigned short* __restrict__ A,
        const unsigned short* __restrict__ Bt, float* __restrict__ ACC,
        int M, int N, int K, int Kc) {
    __shared__ unsigned short As[64][40];
    __shared__ unsigned short Bs[256][40];
    int tid = threadIdx.x;
    int bm = blockIdx.y * 64, bn = blockIdx.x * 256;
    int kbeg = blockIdx.z * Kc, kend = kbeg + Kc;
    int lane = tid & 63, wv = tid >> 6;
    int lrow = lane & 15, lq = lane >> 4;
    floatx4 acc[4][4] = {};
    int sm = tid >> 2, skq = (tid & 3) * 8;
    const unsigned short* Ap = A + (size_t)(bm + sm) * K + skq;
    const unsigned short* Bp0 = Bt + (size_t)(bn + sm) * K + skq;
    const unsigned short* Bp1 = Bp0 + (size_t)64 * K;
    const unsigned short* Bp2 = Bp0 + (size_t)128 * K;
    const unsigned short* Bp3 = Bp0 + (size_t)192 * K;
    short8 av  = *(const short8*)(Ap + kbeg);
    short8 bv0 = *(const short8*)(Bp0 + kbeg);
    short8 bv1 = *(const short8*)(Bp1 + kbeg);
    short8 bv2 = *(const short8*)(Bp2 + kbeg);
    short8 bv3 = *(const short8*)(Bp3 + kbeg);
    for (int k0 = kbeg; k0 < kend; k0 += 32) {
        *(short8*)&As[sm][skq]        = av;
        *(short8*)&Bs[sm][skq]        = bv0;
        *(short8*)&Bs[sm + 64][skq]   = bv1;
        *(short8*)&Bs[sm + 128][skq]  = bv2;
        *(short8*)&Bs[sm + 192][skq]  = bv3;
        __syncthreads();
        if (k0 + 32 < kend) {
            av  = *(const short8*)(Ap + k0 + 32);
            bv0 = *(const short8*)(Bp0 + k0 + 32);
            bv1 = *(const short8*)(Bp1 + k0 + 32);
            bv2 = *(const short8*)(Bp2 + k0 + 32);
            bv3 = *(const short8*)(Bp3 + k0 + 32);
        }
        short8 aF[4], bF[4];
#pragma unroll
        for (int mi = 0; mi < 4; ++mi)
            aF[mi] = *(const short8*)&As[mi * 16 + lrow][lq * 8];
#pragma unroll
        for (int ni = 0; ni < 4; ++ni)
            bF[ni] = *(const short8*)&Bs[wv * 64 + ni * 16 + lrow][lq * 8];
#pragma unroll
        for (int mi = 0; mi < 4; ++mi)
#pragma unroll
            for (int ni = 0; ni < 4; ++ni)
                acc[mi][ni] = __builtin_amdgcn_mfma_f32_16x16x32_bf16(aF[mi], bF[ni], acc[mi][ni], 0, 0, 0);
        __syncthreads();
    }
#pragma unroll
    for (int mi = 0; mi < 4; ++mi)
#pragma unroll
        for (int ni = 0; ni < 4; ++ni)
#pragma unroll
            for (int r = 0; r < 4; ++r) {
                int grow = bm + mi * 16 + lq * 4 + r;
                int gcol = bn + wv * 64 + ni * 16 + lrow;
                unsafeAtomicAdd(&ACC[(size_t)grow * N + gcol], acc[mi][ni][r]);
            }
}

// ---- ACC (N=256) read + re-zero + bf16 cast + per-head src/dst scores, block/row ----
__global__ __launch_bounds__(256) void k_red_scores(float* __restrict__ ACC,
        const float* __restrict__ asrc, const float* __restrict__ adst,
        unsigned short* __restrict__ HPb, float* __restrict__ SRC, float* __restrict__ DST) {
    int row = blockIdx.x, tid = threadIdx.x;
    size_t idx = (size_t)row * 256 + tid;
    float v = ACC[idx];
    ACC[idx] = 0.f;                       // re-zero for the next GEMM's accumulation
    HPb[idx] = f2bf(v);
    float s = v * asrc[tid], d = v * adst[tid];
    for (int o = 16; o; o >>= 1) { s += __shfl_xor(s, o); d += __shfl_xor(d, o); }
    if ((tid & 31) == 0) {
        int h = tid >> 5;
        SRC[row * 8 + h] = s;
        DST[row * 8 + h] = d;
    }
}

// ------- attn layers 0/1: out = elu(agg + X); optional fused layer-2 scores -------
__global__ __launch_bounds__(256) void k_attn_small_f(const unsigned short* __restrict__ hp,
        const float* __restrict__ src, const float* __restrict__ dst,
        const int* __restrict__ nbr, const int* __restrict__ cnts,
        const float* __restrict__ X, float* __restrict__ Hout,
        unsigned short* __restrict__ Hb,
        const float* __restrict__ WS2, const float* __restrict__ WD2,
        float* __restrict__ SRC2, float* __restrict__ DST2) {
    int row = blockIdx.x;
    int tid = threadIdx.x;
    int rb = row & ~(S_ - 1);
    __shared__ int nb[MAXDEG];
    __shared__ float ss[8];
    __shared__ float ew[MAXDEG * 9];
    __shared__ float pr[4][16];
    int cnt = cnts[row];
    for (int t = tid; t < cnt; t += 256) nb[t] = nbr[row * MAXDEG + t];
    if (tid < 8) ss[tid] = src[row * H_ + tid];
    __syncthreads();
    for (int idx = tid; idx < cnt * 8; idx += 256) {
        int n = idx >> 3, h = idx & 7;
        int j = nb[n];
        float e = ss[h] + dst[(rb + j) * H_ + h];
        ew[n * 9 + h] = e > 0.f ? e : LRELU_ALPHA * e;
    }
    __syncthreads();
    {
        int lane = tid & 63, wv = tid >> 6;
        int h = wv * 2 + (lane >> 5), sub = lane & 31;
        float m = -1e30f;
        for (int n = sub; n < cnt; n += 32) m = fmaxf(m, ew[n * 9 + h]);
        for (int o = 16; o; o >>= 1) m = fmaxf(m, __shfl_xor(m, o));
        float s = 0.f;
        for (int n = sub; n < cnt; n += 32) {
            float v = __expf(ew[n * 9 + h] - m); ew[n * 9 + h] = v; s += v;
        }
        for (int o = 16; o; o >>= 1) s += __shfl_xor(s, o);
        float inv = s > 0.f ? 1.f / s : 0.f;
        for (int n = sub; n < cnt; n += 32) ew[n * 9 + h] *= inv;
    }
    __syncthreads();
    int h = tid >> 5;
    float acc0 = 0.f, acc1 = 0.f, acc2 = 0.f, acc3 = 0.f;
    const unsigned short* hpb = hp + (size_t)rb * 256;
    int n = 0;
    for (; n + 3 < cnt; n += 4) {
        int j0 = nb[n], j1 = nb[n + 1], j2 = nb[n + 2], j3 = nb[n + 3];
        float w0 = ew[n * 9 + h], w1 = ew[(n + 1) * 9 + h];
        float w2 = ew[(n + 2) * 9 + h], w3 = ew[(n + 3) * 9 + h];
        acc0 += w0 * bf2f(hpb[(size_t)j0 * 256 + tid]);
        acc1 += w1 * bf2f(hpb[(size_t)j1 * 256 + tid]);
        acc2 += w2 * bf2f(hpb[(size_t)j2 * 256 + tid]);
        acc3 += w3 * bf2f(hpb[(size_t)j3 * 256 + tid]);
    }
    for (; n < cnt; ++n)
        acc0 += ew[n * 9 + h] * bf2f(hpb[(size_t)nb[n] * 256 + tid]);
    float ov = (acc0 + acc1) + (acc2 + acc3) + X[(size_t)row * 256 + tid];
    ov = ov > 0.f ? ov : (__expf(ov) - 1.f);
    Hout[(size_t)row * 256 + tid] = ov;
    Hb[(size_t)row * 256 + tid] = f2bf(ov);
    if (WS2 != nullptr) {
        int lane = tid & 63, wv = tid >> 6;
#pragma unroll
        for (int hh = 0; hh < 8; ++hh) {
            float sP = ov * WS2[hh * 256 + tid];
            float dP = ov * WD2[hh * 256 + tid];
            for (int o = 32; o; o >>= 1) { sP += __shfl_xor(sP, o); dP += __shfl_xor(dP, o); }
            if (lane == 0) { pr[wv][hh * 2] = sP; pr[wv][hh * 2 + 1] = dP; }
        }
        __syncthreads();
        if (tid < 16) {
            float tv = pr[0][tid] + pr[1][tid] + pr[2][tid] + pr[3][tid];
            if ((tid & 1) == 0) SRC2[row * 8 + (tid >> 1)] = tv;
            else                DST2[row * 8 + (tid >> 1)] = tv;
        }
    }
}

// ------- layer-2 aggregation: thread = 2 dims x 4 heads; ew pitch 8 (b128 reads) -------
__global__ __launch_bounds__(256) void k_attn_Y(const unsigned short* __restrict__ Hb,
        const float* __restrict__ src2, const float* __restrict__ dst2,
        const int* __restrict__ nbr, const int* __restrict__ cnts,
        unsigned short* __restrict__ Ycat) {
    int row = blockIdx.x;
    int tid = threadIdx.x;
    int rb = row & ~(S_ - 1);
    __shared__ int nb[MAXDEG];
    __shared__ float ss[8];
    __shared__ float ew[MAXDEG * 8];
    int cnt = cnts[row];
    for (int t = tid; t < cnt; t += 256) nb[t] = nbr[row * MAXDEG + t];
    if (tid < 8) ss[tid] = src2[row * H_ + tid];
    __syncthreads();
    for (int idx = tid; idx < cnt * 8; idx += 256) {
        int n = idx >> 3, h = idx & 7;
        int j = nb[n];
        float e = ss[h] + dst2[(rb + j) * H_ + h];
        ew[n * 8 + h] = e > 0.f ? e : LRELU_ALPHA * e;
    }
    __syncthreads();
    {
        int lane = tid & 63, wv = tid >> 6;
        int h = wv * 2 + (lane >> 5), sub = lane & 31;
        float m = -1e30f;
        for (int n = sub; n < cnt; n += 32) m = fmaxf(m, ew[n * 8 + h]);
        for (int o = 16; o; o >>= 1) m = fmaxf(m, __shfl_xor(m, o));
        float s = 0.f;
        for (int n = sub; n < cnt; n += 32) {
            float v = __expf(ew[n * 8 + h] - m); ew[n * 8 + h] = v; s += v;
        }
        for (int o = 16; o; o >>= 1) s += __shfl_xor(s, o);
        float inv = s > 0.f ? 0.125f / s : 0.f;
        for (int n = sub; n < cnt; n += 32) ew[n * 8 + h] *= inv;
    }
    __syncthreads();
    int dp = tid & 127, hg = tid >> 7;
    const unsigned short* hbase = Hb + (size_t)rb * 256 + 2 * dp;
    const float* ewh = ew + hg * 4;
    float a0x = 0.f, a0y = 0.f, a0z = 0.f, a0w = 0.f;
    float a1x = 0.f, a1y = 0.f, a1z = 0.f, a1w = 0.f;
    int n = 0;
    for (; n + 3 < cnt; n += 4) {
        int j0 = nb[n], j1 = nb[n + 1], j2 = nb[n + 2], j3 = nb[n + 3];
        unsigned int p0 = *(const unsigned int*)(hbase + (size_t)j0 * 256);
        unsigned int p1 = *(const unsigned int*)(hbase + (size_t)j1 * 256);
        unsigned int p2 = *(const unsigned int*)(hbase + (size_t)j2 * 256);
        unsigned int p3 = *(const unsigned int*)(hbase + (size_t)j3 * 256);
        float4 w0 = *(const float4*)(ewh + n * 8);
        float4 w1 = *(const float4*)(ewh + (n + 1) * 8);
        float4 w2 = *(const float4*)(ewh + (n + 2) * 8);
        float4 w3 = *(const float4*)(ewh + (n + 3) * 8);
        float v0a = bf2f((unsigned short)p0), v0b = bf2f((unsigned short)(p0 >> 16));
        float v1a = bf2f((unsigned short)p1), v1b = bf2f((unsigned short)(p1 >> 16));
        float v2a = bf2f((unsigned short)p2), v2b = bf2f((unsigned short)(p2 >> 16));
        float v3a = bf2f((unsigned short)p3), v3b = bf2f((unsigned short)(p3 >> 16));
        a0x += w0.x * v0a + w1.x * v1a + w2.x * v2a + w3.x * v3a;
        a0y += w0.y * v0a + w1.y * v1a + w2.y * v2a + w3.y * v3a;
        a0z += w0.z * v0a + w1.z * v1a + w2.z * v2a + w3.z * v3a;
        a0w += w0.w * v0a + w1.w * v1a + w2.w * v2a + w3.w * v3a;
        a1x += w0.x * v0b + w1.x * v1b + w2.x * v2b + w3.x * v3b;
        a1y += w0.y * v0b + w1.y * v1b + w2.y * v2b + w3.y * v3b;
        a1z += w0.z * v0b + w1.z * v1b + w2.z * v2b + w3.z * v3b;
        a1w += w0.w * v0b + w1.w * v1b + w2.w * v2b + w3.w * v3b;
    }
    for (; n < cnt; ++n) {
        int j = nb[n];
        unsigned int p = *(const unsigned int*)(hbase + (size_t)j * 256);
        float4 w = *(const float4*)(ewh + n * 8);
        float va = bf2f((unsigned short)p), vb = bf2f((unsigned short)(p >> 16));
        a0x += w.x * va; a0y += w.y * va; a0z += w.z * va; a0w += w.w * va;
        a1x += w.x * vb; a1y += w.y * vb; a1z += w.z * vb; a1w += w.w * vb;
    }
    unsigned short* yb = Ycat + (size_t)row * 2048 + (hg * 4) * 256 + 2 * dp;
    ushort2 u;
    u.x = f2bf(a0x); u.y = f2bf(a1x); *(ushort2*)(yb)         = u;
    u.x = f2bf(a0y); u.y = f2bf(a1y); *(ushort2*)(yb + 256)   = u;
    u.x = f2bf(a0z); u.y = f2bf(a1z); *(ushort2*)(yb + 512)   = u;
    u.x = f2bf(a0w); u.y = f2bf(a1w); *(ushort2*)(yb + 768)   = u;
}

// ------- ACC read + re-zero + residual + LayerNorm, fp32 + bf16 out -------
__global__ __launch_bounds__(256) void k_ln_red(float* __restrict__ ACC,
        const float* __restrict__ Hres, const float* __restrict__ g,
        const float* __restrict__ bta, float* __restrict__ HLN,
        unsigned short* __restrict__ HLNb) {
    int row = blockIdx.x * 4 + (threadIdx.x >> 6);
    int lane = threadIdx.x & 63;
    float4 v = ((const float4*)(Hres + (size_t)row * 256))[lane];
    float4* ap = (float4*)(ACC + (size_t)row * 256) + lane;
    float4 p = *ap;
    *ap = make_float4(0.f, 0.f, 0.f, 0.f);   // re-zero for FFN2's accumulation
    v.x += p.x; v.y += p.y; v.z += p.z; v.w += p.w;
    float s = v.x + v.y + v.z + v.w;
    float q = v.x * v.x + v.y * v.y + v.z * v.z + v.w * v.w;
    for (int o = 32; o; o >>= 1) { s += __shfl_xor(s, o); q += __shfl_xor(q, o); }
    float mu = s * (1.f / 256.f);
    float var = q * (1.f / 256.f) - mu * mu;
    if (var < 0.f) var = 0.f;
    float rs = rsqrtf(var + 1e-5f);
    float4 gg = ((const float4*)g)[lane];
    float4 bb = ((const float4*)bta)[lane];
    float4 o;
    o.x = (v.x - mu) * rs * gg.x + bb.x;
    o.y = (v.y - mu) * rs * gg.y + bb.y;
    o.z = (v.z - mu) * rs * gg.z + bb.z;
    o.w = (v.w - mu) * rs * gg.w + bb.w;
    ((float4*)(HLN + (size_t)row * 256))[lane] = o;
    ushort4 ob; ob.x = f2bf(o.x); ob.y = f2bf(o.y); ob.z = f2bf(o.z); ob.w = f2bf(o.w);
    ((ushort4*)(HLNb + (size_t)row * 256))[lane] = ob;
}

// ---------------- ACC2 read + bias + gelu -> bf16 (single-use, no re-zero) ----------------
__global__ void k_red_gelu(const float* __restrict__ ACC2, const float* __restrict__ b1,
                           unsigned short* __restrict__ out, int n, int cmask4) {
    int i = blockIdx.x * blockDim.x + threadIdx.x;
    if (i >= (n >> 2)) return;
    float4 s = ((const float4*)ACC2)[i];
    float4 bb = ((const float4*)b1)[i & cmask4];
    float xs[4] = {s.x + bb.x, s.y + bb.y, s.z + bb.z, s.w + bb.w};
    ushort4 u;
    unsigned short* up = (unsigned short*)&u;
#pragma unroll
    for (int q = 0; q < 4; ++q) {
        float x = xs[q];
        float t = tanhf(0.7978845608028654f * (x + 0.044715f * x * x * x));
        up[q] = f2bf(0.5f * x * (1.f + t));
    }
    ((ushort4*)out)[i] = u;
}

// ---------------- ACC read + residual + bias -> fp32 (final; no re-zero) ----------------
__global__ void k_red_final(const float* __restrict__ ACC, const float* __restrict__ HLN,
                            const float* __restrict__ b2, float* __restrict__ out, int n) {
    int i = blockIdx.x * blockDim.x + threadIdx.x;
    if (i >= (n >> 2)) return;
    float4 s = ((const float4*)HLN)[i];
    float4 bb = ((const float4*)b2)[i & 63];
    float4 v = ((const float4*)ACC)[i];
    s.x += bb.x + v.x; s.y += bb.y + v.y; s.z += bb.z + v.z; s.w += bb.w + v.w;
    ((float4*)out)[i] = s;
}

extern "C" void kernel_launch(void* const* d_in, const int* in_sizes, int n_in,
                              void* d_out, int out_size, void* d_ws, size_t ws_size,
                              hipStream_t stream) {
    const float* adj   = (const float*)d_in[0];
    const float* x     = (const float*)d_in[1];
    const float* W0    = (const float*)d_in[2];
    const float* as0   = (const float*)d_in[3];
    const float* ad0   = (const float*)d_in[4];
    const float* W1    = (const float*)d_in[5];
    const float* as1   = (const float*)d_in[6];
    const float* ad1   = (const float*)d_in[7];
    const float* W2    = (const float*)d_in[8];
    const float* as2   = (const float*)d_in[9];
    const float* ad2   = (const float*)d_in[10];
    const float* ln_g  = (const float*)d_in[11];
    const float* ln_b  = (const float*)d_in[12];
    const float* ff_w1 = (const float*)d_in[13];
    const float* ff_b1 = (const float*)d_in[14];
    const float* ff_w2 = (const float*)d_in[15];
    const float* ff_b2 = (const float*)d_in[16];

    float* ws = (float*)d_ws;
    float* H    = ws;                          // [4096,256] f32
    float* HLN  = ws + 1048576;                // [4096,256] f32
    unsigned short* Ycat = (unsigned short*)(ws + 2097152);   // [4096,2048] bf16
    unsigned short* HPb  = (unsigned short*)(ws + 6291456);   // [4096,256] bf16
    unsigned short* xb   = (unsigned short*)(ws + 6815744);
    unsigned short* Hb   = (unsigned short*)(ws + 7340032);
    unsigned short* HLNb = (unsigned short*)(ws + 7864320);
    unsigned short* MIDb = (unsigned short*)(ws + 8388608);   // [4096,512] bf16
    unsigned short* W0t  = (unsigned short*)(ws + 9437184);   // [256,256]
    unsigned short* W1t  = (unsigned short*)(ws + 9469952);
    unsigned short* W2t  = (unsigned short*)(ws + 9502720);   // [256,2048]
    unsigned short* F1t  = (unsigned short*)(ws + 9764864);   // [512,256]
    unsigned short* F2t  = (unsigned short*)(ws + 9830400);   // [256,512]
    float* WS2  = ws + 9895936;                // [8,256]
    float* WD2  = ws + 9897984;                // [8,256]
    float* SRC  = ws + 9900032;                // [4096,8]
    float* DST  = ws + 9932800;
    float* SRC2 = ws + 9965568;                // [4096,8] layer-2 scores
    float* DST2 = ws + 9998336;
    int*   NBR  = (int*)(ws + 10031104);       // [4096,128]
    int*   CNT  = (int*)(ws + 10555392);
    float* ACC  = ws + 12582912;               // [4096,256] f32 atomic accumulator
    float* ACC2 = ws + 13631488;               // [4096,512] f32 atomic accumulator

    // one prep kernel: CSR + casts + transposes + wvec2 + ACC/ACC2 zero-init
    k_prep<<<6792, 256, 0, stream>>>(x, xb, W0, W0t, W1, W1t, W2, W2t,
                                     ff_w1, F1t, ff_w2, F2t, as2, ad2, WS2, WD2,
                                     adj, NBR, CNT, ACC, ACC2);

    // ---- GAT layer 0 ----
    k_gemm_wide<<<dim3(1, 64, 4), 256, 0, stream>>>(xb, W0t, ACC, 4096, 256, 256, 64);
    k_red_scores<<<4096, 256, 0, stream>>>(ACC, as0, ad0, HPb, SRC, DST);
    k_attn_small_f<<<4096, 256, 0, stream>>>(HPb, SRC, DST, NBR, CNT, x, H, Hb,
                                             nullptr, nullptr, nullptr, nullptr);

    // ---- GAT layer 1 (layer-2 scores fused into epilogue) ----
    k_gemm_wide<<<dim3(1, 64, 4), 256, 0, stream>>>(Hb, W1t, ACC, 4096, 256, 256, 64);
    k_red_scores<<<4096, 256, 0, stream>>>(ACC, as1, ad1, HPb, SRC, DST);
    k_attn_small_f<<<4096, 256, 0, stream>>>(HPb, SRC, DST, NBR, CNT, H, H, Hb,
                                             WS2, WD2, SRC2, DST2);

    // ---- GAT layer 2: aggregate H, GEMM with W2 (split 8, atomic), LN fused ----
    k_attn_Y<<<4096, 256, 0, stream>>>(Hb, SRC2, DST2, NBR, CNT, Ycat);
    k_gemm_wide<<<dim3(1, 64, 8), 256, 0, stream>>>(Ycat, W2t, ACC, 4096, 256, 2048, 256);
    k_ln_red<<<1024, 256, 0, stream>>>(ACC, H, ln_g, ln_b, HLN, HLNb);

    // ---- FFN ----
    k_gemm_wide<<<dim3(2, 64, 2), 256, 0, stream>>>(HLNb, F1t, ACC2, 4096, 512, 256, 128);
    k_red_gelu<<<2048, 256, 0, stream>>>(ACC2, ff_b1, MIDb, 2097152, 127);
    k_gemm_wide<<<dim3(1, 64, 4), 256, 0, stream>>>(MIDb, F2t, ACC, 4096, 256, 512, 128);
    k_red_final<<<1024, 256, 0, stream>>>(ACC, HLN, ff_b2, (float*)d_out, 1048576);
}

// Round 12
// 246.930 us; speedup vs baseline: 1.2342x; 1.2342x over previous
//
#include <hip/hip_runtime.h>
#include <hip/hip_bf16.h>

#define B_ 4
#define S_ 1024
#define D_ 256
#define H_ 8
#define LRELU_ALPHA 0.2f
#define MAXDEG 128

typedef __attribute__((ext_vector_type(8))) short short8;
typedef __attribute__((ext_vector_type(4))) float floatx4;

__device__ __forceinline__ float bf2f(unsigned short u) {
    union { unsigned int i; float f; } c; c.i = ((unsigned int)u) << 16; return c.f;
}
__device__ __forceinline__ unsigned short f2bf(float f) {
    union { float f; unsigned int u; } c; c.f = f;
    unsigned int r = (c.u + 0x7FFF + ((c.u >> 16) & 1)) >> 16;
    return (unsigned short)r;
}

// ---------- fused prep: CSR + x-cast + weight transposes + wvec2, one launch ----------
__device__ void castT_body(const float* __restrict__ W, unsigned short* __restrict__ out,
                           int K, int N, int k0, int n0, float (*t)[33], int tid) {
    int tx = tid & 31, ty = tid >> 5;
#pragma unroll
    for (int i = 0; i < 4; ++i)
        t[ty + 8 * i][tx] = W[(size_t)(k0 + ty + 8 * i) * N + n0 + tx];
    __syncthreads();
#pragma unroll
    for (int i = 0; i < 4; ++i)
        out[(size_t)(n0 + ty + 8 * i) * K + k0 + tx] = f2bf(t[tx][ty + 8 * i]);
}

__global__ __launch_bounds__(256) void k_prep(
        const float* __restrict__ x, unsigned short* __restrict__ xb,
        const float* __restrict__ W0, unsigned short* __restrict__ W0t,
        const float* __restrict__ W1, unsigned short* __restrict__ W1t,
        const float* __restrict__ W2, unsigned short* __restrict__ W2t,
        const float* __restrict__ F1, unsigned short* __restrict__ F1t,
        const float* __restrict__ F2, unsigned short* __restrict__ F2t,
        const float* __restrict__ as2, const float* __restrict__ ad2,
        float* __restrict__ WS2, float* __restrict__ WD2,
        const float* __restrict__ adj, int* __restrict__ nbr, int* __restrict__ cnt) {
    __shared__ float t[32][33];
    __shared__ int c;
    int b = blockIdx.x, tid = threadIdx.x;
    if (b < 1024) {                       // x -> bf16
        int i = b * 256 + tid;
        float4 v = ((const float4*)x)[i];
        ushort4 u; u.x = f2bf(v.x); u.y = f2bf(v.y); u.z = f2bf(v.z); u.w = f2bf(v.w);
        ((ushort4*)xb)[i] = u;
    } else if (b < 1088) {                // W0^T
        int i = b - 1024; castT_body(W0, W0t, 256, 256, (i & 7) * 32, (i >> 3) * 32, t, tid);
    } else if (b < 1152) {                // W1^T
        int i = b - 1088; castT_body(W1, W1t, 256, 256, (i & 7) * 32, (i >> 3) * 32, t, tid);
    } else if (b < 1664) {                // W2 per-head transpose
        int i = b - 1152;
        int k0 = (i & 7) * 32, d0 = ((i >> 3) & 7) * 32, h = i >> 6;
        int tx = tid & 31, ty = tid >> 5;
#pragma unroll
        for (int q = 0; q < 4; ++q)
            t[ty + 8 * q][tx] = W2[(size_t)(k0 + ty + 8 * q) * 2048 + h * 256 + d0 + tx];
        __syncthreads();
#pragma unroll
        for (int q = 0; q < 4; ++q)
            W2t[(size_t)(d0 + ty + 8 * q) * 2048 + h * 256 + k0 + tx] = f2bf(t[tx][ty + 8 * q]);
    } else if (b < 1792) {                // ff_w1^T
        int i = b - 1664; castT_body(F1, F1t, 256, 512, (i & 7) * 32, (i >> 3) * 32, t, tid);
    } else if (b < 1920) {                // ff_w2^T
        int i = b - 1792; castT_body(F2, F2t, 512, 256, (i & 15) * 32, (i >> 4) * 32, t, tid);
    } else if (b < 1928) {                // wvec2
        int h = b - 1920, k = tid;
        const float* wrow = W2 + (size_t)k * 2048 + h * 256;
        float s = 0.f, d = 0.f;
        for (int dd = 0; dd < 256; ++dd) {
            float w = wrow[dd];
            s += w * as2[h * 256 + dd];
            d += w * ad2[h * 256 + dd];
        }
        WS2[h * 256 + k] = s;
        WD2[h * 256 + k] = d;
    } else {                              // CSR build (float4 scan)
        int row = b - 1928;
        if (tid == 0) c = 0;
        __syncthreads();
        float4 a4 = ((const float4*)(adj + (size_t)row * S_))[tid];
#pragma unroll
        for (int q = 0; q < 4; ++q) {
            float a = q == 0 ? a4.x : q == 1 ? a4.y : q == 2 ? a4.z : a4.w;
            if (a > 0.f) {
                int s = atomicAdd(&c, 1);
                if (s < MAXDEG) nbr[row * MAXDEG + s] = tid * 4 + q;
            }
        }
        __syncthreads();
        if (tid == 0) cnt[row] = c < MAXDEG ? c : MAXDEG;
    }
}

// ------- wide-tile split-K MFMA GEMM: tile 64M x 256N, 4 waves x (4x4 accs) -------
__global__ __launch_bounds__(256) void k_gemm_wide(const unsigned short* __restrict__ A,
        const unsigned short* __restrict__ Bt, float* __restrict__ P,
        int M, int N, int K, int Kc) {
    __shared__ unsigned short As[64][40];
    __shared__ unsigned short Bs[256][40];
    int tid = threadIdx.x;
    int bm = blockIdx.y * 64, bn = blockIdx.x * 256;
    int kbeg = blockIdx.z * Kc, kend = kbeg + Kc;
    int lane = tid & 63, wv = tid >> 6;
    int lrow = lane & 15, lq = lane >> 4;
    floatx4 acc[4][4] = {};
    int sm = tid >> 2, skq = (tid & 3) * 8;
    const unsigned short* Ap = A + (size_t)(bm + sm) * K + skq;
    const unsigned short* Bp0 = Bt + (size_t)(bn + sm) * K + skq;
    const unsigned short* Bp1 = Bp0 + (size_t)64 * K;
    const unsigned short* Bp2 = Bp0 + (size_t)128 * K;
    const unsigned short* Bp3 = Bp0 + (size_t)192 * K;
    short8 av  = *(const short8*)(Ap + kbeg);
    short8 bv0 = *(const short8*)(Bp0 + kbeg);
    short8 bv1 = *(const short8*)(Bp1 + kbeg);
    short8 bv2 = *(const short8*)(Bp2 + kbeg);
    short8 bv3 = *(const short8*)(Bp3 + kbeg);
    for (int k0 = kbeg; k0 < kend; k0 += 32) {
        *(short8*)&As[sm][skq]        = av;
        *(short8*)&Bs[sm][skq]        = bv0;
        *(short8*)&Bs[sm + 64][skq]   = bv1;
        *(short8*)&Bs[sm + 128][skq]  = bv2;
        *(short8*)&Bs[sm + 192][skq]  = bv3;
        __syncthreads();
        if (k0 + 32 < kend) {
            av  = *(const short8*)(Ap + k0 + 32);
            bv0 = *(const short8*)(Bp0 + k0 + 32);
            bv1 = *(const short8*)(Bp1 + k0 + 32);
            bv2 = *(const short8*)(Bp2 + k0 + 32);
            bv3 = *(const short8*)(Bp3 + k0 + 32);
        }
        short8 aF[4], bF[4];
#pragma unroll
        for (int mi = 0; mi < 4; ++mi)
            aF[mi] = *(const short8*)&As[mi * 16 + lrow][lq * 8];
#pragma unroll
        for (int ni = 0; ni < 4; ++ni)
            bF[ni] = *(const short8*)&Bs[wv * 64 + ni * 16 + lrow][lq * 8];
#pragma unroll
        for (int mi = 0; mi < 4; ++mi)
#pragma unroll
            for (int ni = 0; ni < 4; ++ni)
                acc[mi][ni] = __builtin_amdgcn_mfma_f32_16x16x32_bf16(aF[mi], bF[ni], acc[mi][ni], 0, 0, 0);
        __syncthreads();
    }
    float* out = P + (size_t)blockIdx.z * M * N;
#pragma unroll
    for (int mi = 0; mi < 4; ++mi)
#pragma unroll
        for (int ni = 0; ni < 4; ++ni)
#pragma unroll
            for (int r = 0; r < 4; ++r) {
                int grow = bm + mi * 16 + lq * 4 + r;
                int gcol = bn + wv * 64 + ni * 16 + lrow;
                out[(size_t)grow * N + gcol] = acc[mi][ni][r];
            }
}

// ---- fused: split-reduce (N=256) + bf16 cast + per-head src/dst scores, block/row ----
__global__ __launch_bounds__(256) void k_red_scores(const float* __restrict__ P, int nsplit,
        const float* __restrict__ asrc, const float* __restrict__ adst,
        unsigned short* __restrict__ HPb, float* __restrict__ SRC, float* __restrict__ DST) {
    int row = blockIdx.x, tid = threadIdx.x;
    float v = P[(size_t)row * 256 + tid];
    for (int sp = 1; sp < nsplit; ++sp)
        v += P[(size_t)sp * 1048576 + (size_t)row * 256 + tid];
    HPb[(size_t)row * 256 + tid] = f2bf(v);
    float s = v * asrc[tid], d = v * adst[tid];
    for (int o = 16; o; o >>= 1) { s += __shfl_xor(s, o); d += __shfl_xor(d, o); }
    if ((tid & 31) == 0) {
        int h = tid >> 5;
        SRC[row * 8 + h] = s;
        DST[row * 8 + h] = d;
    }
}

// ------- attn layers 0/1: 2 rows/block, 2 dims/thread; out = elu(agg + X) -------
__global__ __launch_bounds__(256) void k_attn_small_f(const unsigned short* __restrict__ hp,
        const float* __restrict__ src, const float* __restrict__ dst,
        const int* __restrict__ nbr, const int* __restrict__ cnts,
        const float* __restrict__ X, float* __restrict__ Hout,
        unsigned short* __restrict__ Hb,
        const float* __restrict__ WS2, const float* __restrict__ WD2,
        float* __restrict__ SRC2, float* __restrict__ DST2) {
    int tid = threadIdx.x;
    int half = tid >> 7;                  // which row of the pair
    int sub = tid & 127;
    int row = blockIdx.x * 2 + half;
    int rb = row & ~(S_ - 1);
    __shared__ int nb[2][MAXDEG];
    __shared__ float ss[2][8];
    __shared__ float ew[2][MAXDEG * 9];
    __shared__ float pr[2][2][16];
    int cnt = cnts[row];
    for (int t = sub; t < cnt; t += 128) nb[half][t] = nbr[row * MAXDEG + t];
    if (sub < 8) ss[half][sub] = src[row * H_ + sub];
    __syncthreads();
    for (int idx = sub; idx < cnt * 8; idx += 128) {
        int n = idx >> 3, h = idx & 7;
        int j = nb[half][n];
        float e = ss[half][h] + dst[(rb + j) * H_ + h];
        ew[half][n * 9 + h] = e > 0.f ? e : LRELU_ALPHA * e;
    }
    __syncthreads();
    // per-head softmax: 16-lane group per head (2 waves per row-half, 4 heads each)
    {
        int wv2 = sub >> 6, lane = sub & 63;
        int h = wv2 * 4 + (lane >> 4), s16 = lane & 15;
        float m = -1e30f;
        for (int n = s16; n < cnt; n += 16) m = fmaxf(m, ew[half][n * 9 + h]);
        for (int o = 8; o; o >>= 1) m = fmaxf(m, __shfl_xor(m, o));
        float s = 0.f;
        for (int n = s16; n < cnt; n += 16) {
            float v = __expf(ew[half][n * 9 + h] - m); ew[half][n * 9 + h] = v; s += v;
        }
        for (int o = 8; o; o >>= 1) s += __shfl_xor(s, o);
        float inv = s > 0.f ? 1.f / s : 0.f;
        for (int n = s16; n < cnt; n += 16) ew[half][n * 9 + h] *= inv;
    }
    __syncthreads();
    // gather: thread owns dims (d0, d0+1), same head h = d0>>5
    int d0 = sub * 2;
    int h = sub >> 4;
    const unsigned short* hpb = hp + (size_t)rb * 256 + d0;
    const float* ewr = ew[half];
    float aA0 = 0.f, aA1 = 0.f, aB0 = 0.f, aB1 = 0.f;
    float aC0 = 0.f, aC1 = 0.f, aD0 = 0.f, aD1 = 0.f;
    int n = 0;
    for (; n + 3 < cnt; n += 4) {
        int j0 = nb[half][n], j1 = nb[half][n + 1];
        int j2 = nb[half][n + 2], j3 = nb[half][n + 3];
        unsigned int p0 = *(const unsigned int*)(hpb + (size_t)j0 * 256);
        unsigned int p1 = *(const unsigned int*)(hpb + (size_t)j1 * 256);
        unsigned int p2 = *(const unsigned int*)(hpb + (size_t)j2 * 256);
        unsigned int p3 = *(const unsigned int*)(hpb + (size_t)j3 * 256);
        float w0 = ewr[n * 9 + h], w1 = ewr[(n + 1) * 9 + h];
        float w2 = ewr[(n + 2) * 9 + h], w3 = ewr[(n + 3) * 9 + h];
        aA0 += w0 * bf2f((unsigned short)p0); aA1 += w0 * bf2f((unsigned short)(p0 >> 16));
        aB0 += w1 * bf2f((unsigned short)p1); aB1 += w1 * bf2f((unsigned short)(p1 >> 16));
        aC0 += w2 * bf2f((unsigned short)p2); aC1 += w2 * bf2f((unsigned short)(p2 >> 16));
        aD0 += w3 * bf2f((unsigned short)p3); aD1 += w3 * bf2f((unsigned short)(p3 >> 16));
    }
    for (; n < cnt; ++n) {
        int j = nb[half][n];
        unsigned int p = *(const unsigned int*)(hpb + (size_t)j * 256);
        float w = ewr[n * 9 + h];
        aA0 += w * bf2f((unsigned short)p); aA1 += w * bf2f((unsigned short)(p >> 16));
    }
    float2 xv = *(const float2*)(X + (size_t)row * 256 + d0);
    float ov0 = (aA0 + aB0) + (aC0 + aD0) + xv.x;
    float ov1 = (aA1 + aB1) + (aC1 + aD1) + xv.y;
    ov0 = ov0 > 0.f ? ov0 : (__expf(ov0) - 1.f);
    ov1 = ov1 > 0.f ? ov1 : (__expf(ov1) - 1.f);
    *(float2*)(Hout + (size_t)row * 256 + d0) = make_float2(ov0, ov1);
    ushort2 ub; ub.x = f2bf(ov0); ub.y = f2bf(ov1);
    *(ushort2*)(Hb + (size_t)row * 256 + d0) = ub;
    // fused layer-2 scores (layer 1 only)
    if (WS2 != nullptr) {
        int wv2 = sub >> 6, lane = sub & 63;
#pragma unroll
        for (int hh = 0; hh < 8; ++hh) {
            float sP = ov0 * WS2[hh * 256 + d0] + ov1 * WS2[hh * 256 + d0 + 1];
            float dP = ov0 * WD2[hh * 256 + d0] + ov1 * WD2[hh * 256 + d0 + 1];
            for (int o = 32; o; o >>= 1) { sP += __shfl_xor(sP, o); dP += __shfl_xor(dP, o); }
            if (lane == 0) { pr[half][wv2][hh * 2] = sP; pr[half][wv2][hh * 2 + 1] = dP; }
        }
        __syncthreads();
        if (sub < 16) {
            float tv = pr[half][0][sub] + pr[half][1][sub];
            if ((sub & 1) == 0) SRC2[row * 8 + (sub >> 1)] = tv;
            else                DST2[row * 8 + (sub >> 1)] = tv;
        }
    }
}

// ------- layer-2 aggregation: thread = 2 dims x 4 heads; ew pitch 8 (b128 reads) -------
__global__ __launch_bounds__(256) void k_attn_Y(const unsigned short* __restrict__ Hb,
        const float* __restrict__ src2, const float* __restrict__ dst2,
        const int* __restrict__ nbr, const int* __restrict__ cnts,
        unsigned short* __restrict__ Ycat) {
    int row = blockIdx.x;
    int tid = threadIdx.x;
    int rb = row & ~(S_ - 1);
    __shared__ int nb[MAXDEG];
    __shared__ float ss[8];
    __shared__ float ew[MAXDEG * 8];
    int cnt = cnts[row];
    for (int t = tid; t < cnt; t += 256) nb[t] = nbr[row * MAXDEG + t];
    if (tid < 8) ss[tid] = src2[row * H_ + tid];
    __syncthreads();
    for (int idx = tid; idx < cnt * 8; idx += 256) {
        int n = idx >> 3, h = idx & 7;
        int j = nb[n];
        float e = ss[h] + dst2[(rb + j) * H_ + h];
        ew[n * 8 + h] = e > 0.f ? e : LRELU_ALPHA * e;
    }
    __syncthreads();
    {
        int lane = tid & 63, wv = tid >> 6;
        int h = wv * 2 + (lane >> 5), sub = lane & 31;
        float m = -1e30f;
        for (int n = sub; n < cnt; n += 32) m = fmaxf(m, ew[n * 8 + h]);
        for (int o = 16; o; o >>= 1) m = fmaxf(m, __shfl_xor(m, o));
        float s = 0.f;
        for (int n = sub; n < cnt; n += 32) {
            float v = __expf(ew[n * 8 + h] - m); ew[n * 8 + h] = v; s += v;
        }
        for (int o = 16; o; o >>= 1) s += __shfl_xor(s, o);
        float inv = s > 0.f ? 0.125f / s : 0.f;
        for (int n = sub; n < cnt; n += 32) ew[n * 8 + h] *= inv;
    }
    __syncthreads();
    int dp = tid & 127, hg = tid >> 7;
    const unsigned short* hbase = Hb + (size_t)rb * 256 + 2 * dp;
    const float* ewh = ew + hg * 4;
    float a0x = 0.f, a0y = 0.f, a0z = 0.f, a0w = 0.f;
    float a1x = 0.f, a1y = 0.f, a1z = 0.f, a1w = 0.f;
    int n = 0;
    for (; n + 3 < cnt; n += 4) {
        int j0 = nb[n], j1 = nb[n + 1], j2 = nb[n + 2], j3 = nb[n + 3];
        unsigned int p0 = *(const unsigned int*)(hbase + (size_t)j0 * 256);
        unsigned int p1 = *(const unsigned int*)(hbase + (size_t)j1 * 256);
        unsigned int p2 = *(const unsigned int*)(hbase + (size_t)j2 * 256);
        unsigned int p3 = *(const unsigned int*)(hbase + (size_t)j3 * 256);
        float4 w0 = *(const float4*)(ewh + n * 8);
        float4 w1 = *(const float4*)(ewh + (n + 1) * 8);
        float4 w2 = *(const float4*)(ewh + (n + 2) * 8);
        float4 w3 = *(const float4*)(ewh + (n + 3) * 8);
        float v0a = bf2f((unsigned short)p0), v0b = bf2f((unsigned short)(p0 >> 16));
        float v1a = bf2f((unsigned short)p1), v1b = bf2f((unsigned short)(p1 >> 16));
        float v2a = bf2f((unsigned short)p2), v2b = bf2f((unsigned short)(p2 >> 16));
        float v3a = bf2f((unsigned short)p3), v3b = bf2f((unsigned short)(p3 >> 16));
        a0x += w0.x * v0a + w1.x * v1a + w2.x * v2a + w3.x * v3a;
        a0y += w0.y * v0a + w1.y * v1a + w2.y * v2a + w3.y * v3a;
        a0z += w0.z * v0a + w1.z * v1a + w2.z * v2a + w3.z * v3a;
        a0w += w0.w * v0a + w1.w * v1a + w2.w * v2a + w3.w * v3a;
        a1x += w0.x * v0b + w1.x * v1b + w2.x * v2b + w3.x * v3b;
        a1y += w0.y * v0b + w1.y * v1b + w2.y * v2b + w3.y * v3b;
        a1z += w0.z * v0b + w1.z * v1b + w2.z * v2b + w3.z * v3b;
        a1w += w0.w * v0b + w1.w * v1b + w2.w * v2b + w3.w * v3b;
    }
    for (; n < cnt; ++n) {
        int j = nb[n];
        unsigned int p = *(const unsigned int*)(hbase + (size_t)j * 256);
        float4 w = *(const float4*)(ewh + n * 8);
        float va = bf2f((unsigned short)p), vb = bf2f((unsigned short)(p >> 16));
        a0x += w.x * va; a0y += w.y * va; a0z += w.z * va; a0w += w.w * va;
        a1x += w.x * vb; a1y += w.y * vb; a1z += w.z * vb; a1w += w.w * vb;
    }
    unsigned short* yb = Ycat + (size_t)row * 2048 + (hg * 4) * 256 + 2 * dp;
    ushort2 u;
    u.x = f2bf(a0x); u.y = f2bf(a1x); *(ushort2*)(yb)         = u;
    u.x = f2bf(a0y); u.y = f2bf(a1y); *(ushort2*)(yb + 256)   = u;
    u.x = f2bf(a0z); u.y = f2bf(a1z); *(ushort2*)(yb + 512)   = u;
    u.x = f2bf(a0w); u.y = f2bf(a1w); *(ushort2*)(yb + 768)   = u;
}

// ------- split reduce + residual + LayerNorm, fp32 + bf16 out -------
__global__ __launch_bounds__(256) void k_ln_red(const float* __restrict__ P, int nsplit,
        const float* __restrict__ Hres, const float* __restrict__ g,
        const float* __restrict__ bta, float* __restrict__ HLN,
        unsigned short* __restrict__ HLNb) {
    int row = blockIdx.x * 4 + (threadIdx.x >> 6);
    int lane = threadIdx.x & 63;
    float4 v = ((const float4*)(Hres + (size_t)row * 256))[lane];
    for (int sp = 0; sp < nsplit; ++sp) {
        float4 p = ((const float4*)(P + (size_t)sp * 1048576 + (size_t)row * 256))[lane];
        v.x += p.x; v.y += p.y; v.z += p.z; v.w += p.w;
    }
    float s = v.x + v.y + v.z + v.w;
    float q = v.x * v.x + v.y * v.y + v.z * v.z + v.w * v.w;
    for (int o = 32; o; o >>= 1) { s += __shfl_xor(s, o); q += __shfl_xor(q, o); }
    float mu = s * (1.f / 256.f);
    float var = q * (1.f / 256.f) - mu * mu;
    if (var < 0.f) var = 0.f;
    float rs = rsqrtf(var + 1e-5f);
    float4 gg = ((const float4*)g)[lane];
    float4 bb = ((const float4*)bta)[lane];
    float4 o;
    o.x = (v.x - mu) * rs * gg.x + bb.x;
    o.y = (v.y - mu) * rs * gg.y + bb.y;
    o.z = (v.z - mu) * rs * gg.z + bb.z;
    o.w = (v.w - mu) * rs * gg.w + bb.w;
    ((float4*)(HLN + (size_t)row * 256))[lane] = o;
    ushort4 ob; ob.x = f2bf(o.x); ob.y = f2bf(o.y); ob.z = f2bf(o.z); ob.w = f2bf(o.w);
    ((ushort4*)(HLNb + (size_t)row * 256))[lane] = ob;
}

// ---------------- split reduce + bias + gelu -> bf16 ----------------
__global__ void k_red_gelu(const float* __restrict__ P, const float* __restrict__ b1,
                           unsigned short* __restrict__ out, int n, int nsplit, int cmask4) {
    int i = blockIdx.x * blockDim.x + threadIdx.x;
    if (i >= (n >> 2)) return;
    float4 s = ((const float4*)P)[i];
    for (int sp = 1; sp < nsplit; ++sp) {
        float4 v = ((const float4*)(P + (size_t)sp * n))[i];
        s.x += v.x; s.y += v.y; s.z += v.z; s.w += v.w;
    }
    float4 bb = ((const float4*)b1)[i & cmask4];
    float xs[4] = {s.x + bb.x, s.y + bb.y, s.z + bb.z, s.w + bb.w};
    ushort4 u;
    unsigned short* up = (unsigned short*)&u;
#pragma unroll
    for (int q = 0; q < 4; ++q) {
        float x = xs[q];
        float t = tanhf(0.7978845608028654f * (x + 0.044715f * x * x * x));
        up[q] = f2bf(0.5f * x * (1.f + t));
    }
    ((ushort4*)out)[i] = u;
}

// ---------------- split reduce + residual + bias -> fp32 (final) ----------------
__global__ void k_red_final(const float* __restrict__ P, const float* __restrict__ HLN,
                            const float* __restrict__ b2, float* __restrict__ out,
                            int n, int nsplit) {
    int i = blockIdx.x * blockDim.x + threadIdx.x;
    if (i >= (n >> 2)) return;
    float4 s = ((const float4*)HLN)[i];
    float4 bb = ((const float4*)b2)[i & 63];
    s.x += bb.x; s.y += bb.y; s.z += bb.z; s.w += bb.w;
    for (int sp = 0; sp < nsplit; ++sp) {
        float4 v = ((const float4*)(P + (size_t)sp * n))[i];
        s.x += v.x; s.y += v.y; s.z += v.z; s.w += v.w;
    }
    ((float4*)out)[i] = s;
}

extern "C" void kernel_launch(void* const* d_in, const int* in_sizes, int n_in,
                              void* d_out, int out_size, void* d_ws, size_t ws_size,
                              hipStream_t stream) {
    const float* adj   = (const float*)d_in[0];
    const float* x     = (const float*)d_in[1];
    const float* W0    = (const float*)d_in[2];
    const float* as0   = (const float*)d_in[3];
    const float* ad0   = (const float*)d_in[4];
    const float* W1    = (const float*)d_in[5];
    const float* as1   = (const float*)d_in[6];
    const float* ad1   = (const float*)d_in[7];
    const float* W2    = (const float*)d_in[8];
    const float* as2   = (const float*)d_in[9];
    const float* ad2   = (const float*)d_in[10];
    const float* ln_g  = (const float*)d_in[11];
    const float* ln_b  = (const float*)d_in[12];
    const float* ff_w1 = (const float*)d_in[13];
    const float* ff_b1 = (const float*)d_in[14];
    const float* ff_w2 = (const float*)d_in[15];
    const float* ff_b2 = (const float*)d_in[16];

    float* ws = (float*)d_ws;
    float* H    = ws;                          // [4096,256] f32
    float* HLN  = ws + 1048576;                // [4096,256] f32
    unsigned short* Ycat = (unsigned short*)(ws + 2097152);   // [4096,2048] bf16
    unsigned short* HPb  = (unsigned short*)(ws + 6291456);   // [4096,256] bf16
    unsigned short* xb   = (unsigned short*)(ws + 6815744);
    unsigned short* Hb   = (unsigned short*)(ws + 7340032);
    unsigned short* HLNb = (unsigned short*)(ws + 7864320);
    unsigned short* MIDb = (unsigned short*)(ws + 8388608);   // [4096,512] bf16
    unsigned short* W0t  = (unsigned short*)(ws + 9437184);   // [256,256]
    unsigned short* W1t  = (unsigned short*)(ws + 9469952);
    unsigned short* W2t  = (unsigned short*)(ws + 9502720);   // [256,2048]
    unsigned short* F1t  = (unsigned short*)(ws + 9764864);   // [512,256]
    unsigned short* F2t  = (unsigned short*)(ws + 9830400);   // [256,512]
    float* WS2  = ws + 9895936;                // [8,256]
    float* WD2  = ws + 9897984;                // [8,256]
    float* SRC  = ws + 9900032;                // [4096,8]
    float* DST  = ws + 9932800;
    float* SRC2 = ws + 9965568;                // [4096,8] layer-2 scores
    float* DST2 = ws + 9998336;
    int*   NBR  = (int*)(ws + 10031104);       // [4096,128]
    int*   CNT  = (int*)(ws + 10555392);
    float* PP   = ws + 12582912;               // split-K partials, up to [8][4096][256] f32

    // one prep kernel: CSR + casts + transposes + wvec2
    k_prep<<<6024, 256, 0, stream>>>(x, xb, W0, W0t, W1, W1t, W2, W2t,
                                     ff_w1, F1t, ff_w2, F2t, as2, ad2, WS2, WD2,
                                     adj, NBR, CNT);

    // ---- GAT layer 0 ----
    k_gemm_wide<<<dim3(1, 64, 4), 256, 0, stream>>>(xb, W0t, PP, 4096, 256, 256, 64);
    k_red_scores<<<4096, 256, 0, stream>>>(PP, 4, as0, ad0, HPb, SRC, DST);
    k_attn_small_f<<<2048, 256, 0, stream>>>(HPb, SRC, DST, NBR, CNT, x, H, Hb,
                                             nullptr, nullptr, nullptr, nullptr);

    // ---- GAT layer 1 (layer-2 scores fused into epilogue) ----
    k_gemm_wide<<<dim3(1, 64, 4), 256, 0, stream>>>(Hb, W1t, PP, 4096, 256, 256, 64);
    k_red_scores<<<4096, 256, 0, stream>>>(PP, 4, as1, ad1, HPb, SRC, DST);
    k_attn_small_f<<<2048, 256, 0, stream>>>(HPb, SRC, DST, NBR, CNT, H, H, Hb,
                                             WS2, WD2, SRC2, DST2);

    // ---- GAT layer 2: aggregate H, GEMM with W2 (split 4), LN fused ----
    k_attn_Y<<<4096, 256, 0, stream>>>(Hb, SRC2, DST2, NBR, CNT, Ycat);
    k_gemm_wide<<<dim3(1, 64, 4), 256, 0, stream>>>(Ycat, W2t, PP, 4096, 256, 2048, 512);
    k_ln_red<<<1024, 256, 0, stream>>>(PP, 4, H, ln_g, ln_b, HLN, HLNb);

    // ---- FFN ----
    k_gemm_wide<<<dim3(2, 64, 2), 256, 0, stream>>>(HLNb, F1t, PP, 4096, 512, 256, 128);
    k_red_gelu<<<2048, 256, 0, stream>>>(PP, ff_b1, MIDb, 2097152, 2, 127);
    k_gemm_wide<<<dim3(1, 64, 4), 256, 0, stream>>>(MIDb, F2t, PP, 4096, 256, 512, 128);
    k_red_final<<<1024, 256, 0, stream>>>(PP, HLN, ff_b2, (float*)d_out, 1048576, 4);
}